// Round 2
// baseline (1098.557 us; speedup 1.0000x reference)
//
#include <hip/hip_runtime.h>
#include <math.h>

// LSTM: B=512, T=1000, I=64, H=50, gates 4H=200, torch order (i,f,g,o).
// One block per batch row. Thread g in [0,200) owns gate g; its W_ih row
// (16 float4) and zero-padded W_hh row (13 float4) are held in NAMED float4
// registers (round-1 showed arrays get demoted: VGPR_Count=76). x_t and h
// are LDS-broadcast; c lives in registers of threads 0..49.

#define HSZ 50
#define ISZ 64
#define TSZ 1000
#define GSZ 200   // 4*HSZ

__global__ __launch_bounds__(256, 2) void lstm_fused(
    const float* __restrict__ x,      // [B, T, I]
    const float* __restrict__ W_ih,   // [4H, I]
    const float* __restrict__ W_hh,   // [4H, H]
    const float* __restrict__ b_ih,   // [4H]
    const float* __restrict__ b_hh,   // [4H]
    const float* __restrict__ W_out,  // [2, H]
    const float* __restrict__ b_out,  // [2]
    float* __restrict__ out)          // [B, 2]
{
    const int b   = blockIdx.x;
    const int tid = threadIdx.x;

    __shared__ __align__(16) float xs[2][ISZ];   // double-buffered x_t
    __shared__ __align__(16) float hs[52];       // hidden state, padded
    __shared__ __align__(16) float gs[GSZ];      // activated gates

    // ---- Weights as named SSA float4 values (forced into VGPRs) ----
    float4 wi0, wi1, wi2, wi3, wi4, wi5, wi6, wi7,
           wi8, wi9, wi10, wi11, wi12, wi13, wi14, wi15;
    float4 wh0, wh1, wh2, wh3, wh4, wh5, wh6, wh7,
           wh8, wh9, wh10, wh11, wh12;
    float bias = 0.0f, s1 = 1.0f, s2 = 1.0f, s3 = 0.0f;

    if (tid < GSZ) {
        const float4* wi = (const float4*)(W_ih + tid * ISZ);  // 256B row stride, aligned
        wi0 = wi[0];  wi1 = wi[1];  wi2  = wi[2];  wi3  = wi[3];
        wi4 = wi[4];  wi5 = wi[5];  wi6  = wi[6];  wi7  = wi[7];
        wi8 = wi[8];  wi9 = wi[9];  wi10 = wi[10]; wi11 = wi[11];
        wi12 = wi[12]; wi13 = wi[13]; wi14 = wi[14]; wi15 = wi[15];

        const float* wh = W_hh + tid * HSZ;   // 200B stride: scalar loads (alignment)
#define LWH(k) make_float4(wh[4*(k)], wh[4*(k)+1], wh[4*(k)+2], wh[4*(k)+3])
        wh0 = LWH(0);  wh1 = LWH(1);  wh2 = LWH(2);  wh3 = LWH(3);
        wh4 = LWH(4);  wh5 = LWH(5);  wh6 = LWH(6);  wh7 = LWH(7);
        wh8 = LWH(8);  wh9 = LWH(9);  wh10 = LWH(10); wh11 = LWH(11);
#undef LWH
        wh12 = make_float4(wh[48], wh[49], 0.0f, 0.0f);

        bias = b_ih[tid] + b_hh[tid];
        // gate class: [0,100)=i,f sigmoid; [100,150)=g tanh; [150,200)=o sigmoid
        // tanh(v) = 2*sigmoid(2v) - 1  ->  a = s2*sigmoid(s1*v) + s3
        const bool isg = (tid >= 2 * HSZ) && (tid < 3 * HSZ);
        s1 = isg ? 2.0f : 1.0f;
        s2 = isg ? 2.0f : 1.0f;
        s3 = isg ? -1.0f : 0.0f;
    }

    float c_reg = 0.0f;
    if (tid < 52) hs[tid] = 0.0f;    // h0 = 0, incl. pad [50],[51]

    const float* xb = x + (size_t)b * (TSZ * ISZ);
    if (tid < ISZ) xs[0][tid] = xb[tid];
    __syncthreads();

    for (int t = 0; t < TSZ; ++t) {
        const int cur = t & 1;
        const int nxt = cur ^ 1;

        // Prefetch x[t+1] into registers (latency hides under gate compute)
        float xpre = 0.0f;
        const bool pf = (t + 1 < TSZ) && (tid < ISZ);
        if (pf) xpre = xb[(size_t)(t + 1) * ISZ + tid];

        if (tid < GSZ) {
            // 4 accumulators break the dependent-FMA chain (29 deps each)
            float a0 = bias, a1 = 0.0f, a2 = 0.0f, a3 = 0.0f;
            const float4* x4 = (const float4*)(&xs[cur][0]);
#define XSTEP(k, W) { float4 v = x4[k];                    \
            a0 = fmaf(v.x, W.x, a0); a1 = fmaf(v.y, W.y, a1); \
            a2 = fmaf(v.z, W.z, a2); a3 = fmaf(v.w, W.w, a3); }
            XSTEP(0, wi0)  XSTEP(1, wi1)  XSTEP(2, wi2)   XSTEP(3, wi3)
            XSTEP(4, wi4)  XSTEP(5, wi5)  XSTEP(6, wi6)   XSTEP(7, wi7)
            XSTEP(8, wi8)  XSTEP(9, wi9)  XSTEP(10, wi10) XSTEP(11, wi11)
            XSTEP(12, wi12) XSTEP(13, wi13) XSTEP(14, wi14) XSTEP(15, wi15)
#undef XSTEP
            const float4* h4 = (const float4*)(&hs[0]);
#define HSTEP(k, W) { float4 v = h4[k];                    \
            a0 = fmaf(v.x, W.x, a0); a1 = fmaf(v.y, W.y, a1); \
            a2 = fmaf(v.z, W.z, a2); a3 = fmaf(v.w, W.w, a3); }
            HSTEP(0, wh0)  HSTEP(1, wh1)  HSTEP(2, wh2)   HSTEP(3, wh3)
            HSTEP(4, wh4)  HSTEP(5, wh5)  HSTEP(6, wh6)   HSTEP(7, wh7)
            HSTEP(8, wh8)  HSTEP(9, wh9)  HSTEP(10, wh10) HSTEP(11, wh11)
            HSTEP(12, wh12)
#undef HSTEP
            const float acc = (a0 + a1) + (a2 + a3);
            const float u   = s1 * acc;
            const float sig = 1.0f / (1.0f + __expf(-u));
            gs[tid] = fmaf(s2, sig, s3);
        }
        if (pf) xs[nxt][tid] = xpre;
        __syncthreads();   // gates + next-x visible

        if (tid < HSZ) {
            const float ig = gs[tid];
            const float fg = gs[tid + HSZ];
            const float gg = gs[tid + 2 * HSZ];
            const float og = gs[tid + 3 * HSZ];
            c_reg = fmaf(fg, c_reg, ig * gg);
            // tanh(c) = 2*sigmoid(2c) - 1
            const float sg = 1.0f / (1.0f + __expf(-2.0f * c_reg));
            hs[tid] = og * fmaf(2.0f, sg, -1.0f);
        }
        __syncthreads();   // new h visible
    }

    // Final projection: out[b, k] = sum_j h[j] * W_out[k, j] + b_out[k]
    if (tid < 2) {
        float acc = b_out[tid];
        const float* wo = W_out + tid * HSZ;
        #pragma unroll
        for (int j = 0; j < HSZ; ++j) acc = fmaf(hs[j], wo[j], acc);
        out[b * 2 + tid] = acc;
    }
}

extern "C" void kernel_launch(void* const* d_in, const int* in_sizes, int n_in,
                              void* d_out, int out_size, void* d_ws, size_t ws_size,
                              hipStream_t stream) {
    const float* x     = (const float*)d_in[0];
    const float* W_ih  = (const float*)d_in[1];
    const float* W_hh  = (const float*)d_in[2];
    const float* b_ih  = (const float*)d_in[3];
    const float* b_hh  = (const float*)d_in[4];
    const float* W_out = (const float*)d_in[5];
    const float* b_out = (const float*)d_in[6];
    float* out = (float*)d_out;

    const int B = in_sizes[0] / (TSZ * ISZ);   // 512
    hipLaunchKernelGGL(lstm_fused, dim3(B), dim3(256), 0, stream,
                       x, W_ih, W_hh, b_ih, b_hh, W_out, b_out, out);
}